// Round 14
// baseline (54789.160 us; speedup 1.0000x reference)
//
#include <hip/hip_runtime.h>
#include <stdint.h>

#define NBATCH  32
#define NPTS    131072
#define NPOINTS 4096
#define BPB     16           // blocks per batch -> grid = 512 = 2 blocks/CU (co-resident: VGPR<=128)
#define TPB     512          // threads per block
#define PPT     16           // points per thread = NPTS/BPB/TPB
#define PPB     (NPTS / BPB) // 8192

typedef unsigned long long u64;
typedef unsigned int u32;

#define SLOT_STRIDE 8        // u64s -> 64 B between slots

// Slot (per batch, parity, block): word0 = [60:49] it+1 | [48:17] f32 dist bits | [16:0] 131071-gi
//                                  word1 = (ybits<<32)|xbits   word2 = zbits
// Publish: relaxed payload stores, release tag store. Poll: acquire tag, then payload.
// Parity double-buffer: slot rewritten only 2 steps later (all pollers passed).
//
// Distance (bit-exact vs harness reference, proven r9):
//   d = fma(dz,dz, fma(dx,dx, dy*dy)), dy^2 separately rounded; min-index ties.
//
// r9-r13 lesson: allocator targets max-occupancy VGPR budget and evicts big arrays
// (pins only force execution, not residency). Fix: shrink demand to ~90 VGPR
// (PPT=16) and pin budget to 128 via waves_per_eu(4,4) -> demand < budget, no
// eviction, and 16 waves/CU of latency hiding instead of 8.

__global__ __attribute__((amdgpu_flat_work_group_size(TPB, TPB)))
           __attribute__((amdgpu_waves_per_eu(4, 4)))
void fps_kernel(const float* __restrict__ inp, float* __restrict__ out,
                u64* __restrict__ slots)
{
#pragma clang fp contract(off)
    const int bid  = blockIdx.x;
    const int b    = bid & 31;   // batch (all 16 blocks of a batch share XCD bid%8)
    const int j    = bid >> 5;   // block-within-batch 0..15
    const int t    = threadIdx.x;
    const int lane = t & 63;
    const int wid  = t >> 6;

    const float* P  = inp + (size_t)b * NPTS * 3;
    float* outP     = out + (size_t)b * NPOINTS * 3;
    float* outIdx   = out + (size_t)NBATCH * NPOINTS * 3 + (size_t)b * NPOINTS;

    const int base = j * PPB;

    float px[PPT], py[PPT], pz[PPT], dist[PPT];   // 64 data VGPRs, fits 128 budget
#pragma unroll
    for (int k = 0; k < PPT; ++k) {
        const int p = base + k * TPB + t;
        const float* pp = P + (size_t)p * 3;
        px[k] = pp[0]; py[k] = pp[1]; pz[k] = pp[2];
        dist[k] = 1e10f;
    }

    float qx = P[0], qy = P[1], qz = P[2];   // first selected index is 0
    if (j == 0 && t == 0) {
        outP[0] = qx; outP[1] = qy; outP[2] = qz;
        outIdx[0] = 0.0f;                    // whole d_out read back as float32
    }

    u64* myslots = slots + (size_t)b * (2 * BPB * SLOT_STRIDE);

    __shared__ u64 skey[TPB / 64];
    __shared__ u64 sxy[TPB / 64];
    __shared__ u64 sz[TPB / 64];
    __shared__ float sq[3];

    for (int it = 0; it < NPOINTS - 1; ++it) {
        // ---- update running min-dist; thread-local argmax carries its coords ----
        float m = -1.0f; int ki = 0;
        float mx = 0.f, my = 0.f, mz = 0.f;
#pragma unroll
        for (int k = 0; k < PPT; ++k) {
            float dx = px[k] - qx;
            float dy = py[k] - qy;
            float dz = pz[k] - qz;
            float yy = dy * dy;
            asm("" : "+v"(yy));                       // dy^2 stays separately rounded
            float d  = __builtin_fmaf(dz, dz,
                        __builtin_fmaf(dx, dx, yy));  // reference contraction shape
            float nd = fminf(dist[k], d);
            dist[k] = nd;
            bool c = nd > m;                          // first-max (ascending gi)
            m  = c ? nd : m;  ki = c ? k : ki;
            mx = c ? px[k] : mx; my = c ? py[k] : my; mz = c ? pz[k] : mz;
        }
        const int gi = base + ki * TPB + t;
        u64 key = ((u64)__float_as_uint(m) << 17) | (u64)(131071 - gi);

        // ---- wave reduce: max key, then pull winner's coords via ballot+shfl ----
        u64 kmax = key;
#pragma unroll
        for (int s = 1; s < 64; s <<= 1) {
            u64 o = __shfl_xor(kmax, s, 64);
            if (o > kmax) kmax = o;
        }
        int wl = __ffsll(__ballot(key == kmax)) - 1;  // unique (key embeds gi)
        float wx = __shfl(mx, wl, 64), wy = __shfl(my, wl, 64), wz = __shfl(mz, wl, 64);
        if (lane == 0) {
            skey[wid] = kmax;
            sxy[wid]  = ((u64)__float_as_uint(wy) << 32) | __float_as_uint(wx);
            sz[wid]   = __float_as_uint(wz);
        }
        __syncthreads();

        if (wid == 0) {
            // ---- cross-wave (8 entries) ----
            u64 k2 = (lane < TPB / 64) ? skey[lane] : 0ull;
            u64 kk = k2;
#pragma unroll
            for (int s = 1; s < TPB / 64; s <<= 1) {
                u64 o = __shfl_xor(kk, s, 64);
                if (o > kk) kk = o;
            }
            int we = __ffsll(__ballot(k2 == kk && lane < TPB / 64)) - 1;  // winning wave entry
            const int par = it & 1;
            const u64 tag = (u64)(it + 1) << 49;
            if (lane == 0) {
                u64* slot = &myslots[(size_t)(par * BPB + j) * SLOT_STRIDE];
                __hip_atomic_store(&slot[1], sxy[we], __ATOMIC_RELAXED, __HIP_MEMORY_SCOPE_AGENT);
                __hip_atomic_store(&slot[2], sz[we],  __ATOMIC_RELAXED, __HIP_MEMORY_SCOPE_AGENT);
                __hip_atomic_store(&slot[0], tag | kk, __ATOMIC_RELEASE, __HIP_MEMORY_SCOPE_AGENT);
            }
            // ---- poll all BPB slots; winner coords arrive with the poll ----
            u64 tw = 0;
            bool ok = (lane >= BPB);
            int guard = 0;
            while (true) {
                if (!ok) {
                    tw = __hip_atomic_load(&myslots[(size_t)(par * BPB + lane) * SLOT_STRIDE],
                                           __ATOMIC_ACQUIRE, __HIP_MEMORY_SCOPE_AGENT);
                    ok = (tw >> 49) >= (u64)(it + 1);
                }
                if (__all((int)ok)) break;
                if (++guard > (1 << 20)) break;   // hang safeguard (unreachable when co-resident)
            }
            u64 pxy = 0, pzz = 0, k3 = 0;
            if (lane < BPB) {
                u64* slot = &myslots[(size_t)(par * BPB + lane) * SLOT_STRIDE];
                pxy = __hip_atomic_load(&slot[1], __ATOMIC_RELAXED, __HIP_MEMORY_SCOPE_AGENT);
                pzz = __hip_atomic_load(&slot[2], __ATOMIC_RELAXED, __HIP_MEMORY_SCOPE_AGENT);
                k3  = tw & ((1ull << 49) - 1);
            }
            u64 k3m = k3;
#pragma unroll
            for (int s = 1; s < BPB; s <<= 1) {
                u64 o = __shfl_xor(k3m, s, 64);
                if (o > k3m) k3m = o;
            }
            int w3 = __ffsll(__ballot(k3 == k3m && lane < BPB)) - 1;
            u64 wxy = __shfl(pxy, w3, 64);
            u64 wzz = __shfl(pzz, w3, 64);
            if (lane == 0) {
                float nqx = __uint_as_float((u32)wxy);
                float nqy = __uint_as_float((u32)(wxy >> 32));
                float nqz = __uint_as_float((u32)wzz);
                sq[0] = nqx; sq[1] = nqy; sq[2] = nqz;
                if (j == 0) {
                    float* o3 = outP + (size_t)(it + 1) * 3;
                    o3[0] = nqx; o3[1] = nqy; o3[2] = nqz;
                    outIdx[it + 1] = (float)(131071 - (int)(k3m & 0x1FFFF));
                }
            }
        }
        __syncthreads();
        qx = sq[0]; qy = sq[1]; qz = sq[2];
    }
}

extern "C" void kernel_launch(void* const* d_in, const int* in_sizes, int n_in,
                              void* d_out, int out_size, void* d_ws, size_t ws_size,
                              hipStream_t stream)
{
    const float* inp = (const float*)d_in[0];
    float* outp      = (float*)d_out;
    u64* slots       = (u64*)d_ws;

    hipMemsetAsync(d_ws, 0,
                   (size_t)NBATCH * 2 * BPB * SLOT_STRIDE * sizeof(u64), stream);

    fps_kernel<<<NBATCH * BPB, TPB, 0, stream>>>(inp, outp, slots);
}